// Round 12
// baseline (488.366 us; speedup 1.0000x reference)
//
#include <hip/hip_runtime.h>
#include <hip/hip_bf16.h>
#include <cstdint>
#include <cstddef>

#define NN 50000
#define NE 800000
#define DD 128

typedef __attribute__((ext_vector_type(8))) short short8;
typedef __attribute__((ext_vector_type(4))) float f32x4;

__device__ __forceinline__ unsigned short f2bf(float f) {
  unsigned u = __float_as_uint(f);
  u = (u + 0x7FFFu + ((u >> 16) & 1u)) >> 16;
  return (unsigned short)u;
}

// Convert 4 weight matrices [k][col] f32 -> transposed bf16 [col][k] (linear)
__global__ void k_prep(const float* __restrict__ Ws1, const float* __restrict__ Wr,
                       const float* __restrict__ Wm, const float* __restrict__ We,
                       unsigned short* __restrict__ Wt) {
  int i = blockIdx.x * blockDim.x + threadIdx.x;
  for (int idx = i; idx < 4 * DD * DD; idx += gridDim.x * blockDim.x) {
    int m = idx >> 14, r = idx & 16383, col = r >> 7, k = r & 127;
    const float* src = (m == 0) ? Ws1 : (m == 1) ? Wr : (m == 2) ? Wm : We;
    Wt[idx] = f2bf(src[k * DD + col]);
  }
}

__device__ __forceinline__ unsigned cvtpk(float lo, float hi) {
  unsigned r;
  asm("v_cvt_pk_bf16_f32 %0, %1, %2" : "=v"(r) : "v"(lo), "v"(hi));
  return r;
}

__device__ __forceinline__ short8 cvt8(f32x4 f0, f32x4 f1) {
  union { short8 s; unsigned u[4]; } t;
  t.u[0] = cvtpk(f0[0], f0[1]);
  t.u[1] = cvtpk(f0[2], f0[3]);
  t.u[2] = cvtpk(f1[0], f1[1]);
  t.u[3] = cvtpk(f1[2], f1[3]);
  return t.s;
}

__device__ __forceinline__ f32x4 unpk(uint2 u) {
  f32x4 v;
  v[0] = __uint_as_float(u.x << 16);
  v[1] = __uint_as_float(u.x & 0xFFFF0000u);
  v[2] = __uint_as_float(u.y << 16);
  v[3] = __uint_as_float(u.y & 0xFFFF0000u);
  return v;
}

// Stage 32KB W ([col][k] bf16) into LDS. Chunk (col, slot∈[0,16)) of 16B goes to
// col*256 + ((slot^col)&15)*16 — per-read-instruction bank-groups are uniform.
__device__ __forceinline__ void stage_w(const unsigned short* __restrict__ Wt,
                                        char* __restrict__ lds, int tid) {
#pragma unroll
  for (int c = 0; c < 8; ++c) {
    int ci = tid * 8 + c;
    int col = ci >> 4, slot = ci & 15;
    uint4 v = *(const uint4*)(Wt + ci * 8);
    *(uint4*)(lds + col * 256 + ((slot ^ col) & 15) * 16) = v;
  }
}

__device__ __forceinline__ short8 read_w(const char* __restrict__ lds, int col, int slot) {
  return *(const short8*)(lds + col * 256 + ((slot ^ col) & 15) * 16);
}

// Persistent 3-plane node projection. Plane 0 bias = b_s1 + b_e (folded).
// All planes written as packed bf16 (halves gather traffic downstream).
__global__ __launch_bounds__(256, 4) void k_nodeproj(
    const float* __restrict__ nodes, const unsigned short* __restrict__ Wt,
    const float* __restrict__ b_s1, const float* __restrict__ b_r, const float* __restrict__ b_m,
    const float* __restrict__ b_e,
    unsigned* __restrict__ P1h, unsigned* __restrict__ Prh, unsigned* __restrict__ Pmh) {
  __shared__ char ldsW[32768];
  int m = blockIdx.y;
  int tid = threadIdx.x;
  stage_w(Wt + m * 16384, ldsW, tid);
  __syncthreads();
  const float* bias = (m == 0) ? b_s1 : (m == 1) ? b_r : b_m;
  unsigned* P = (m == 0) ? P1h : (m == 1) ? Prh : Pmh;
  int wid = tid >> 6, l = tid & 63;
  int lmod = l & 15, ldiv = l >> 4;
  int wave = blockIdx.x * 4 + wid, nw = gridDim.x * 4;
  for (int b = wave; b < NN / 16; b += nw) {
    int row = b * 16 + lmod;
    const float* nrow = nodes + (size_t)row * DD;
    short8 bb[4];
#pragma unroll
    for (int kk = 0; kk < 4; ++kk) {
      const f32x4* p = (const f32x4*)(nrow + kk * 32 + ldiv * 8);
      bb[kk] = cvt8(p[0], p[1]);
    }
    f32x4 acc[8] = {};
#pragma unroll
    for (int kk = 0; kk < 4; ++kk) {
#pragma unroll
      for (int rb = 0; rb < 8; ++rb) {
        short8 a = read_w(ldsW, rb * 16 + lmod, kk * 4 + ldiv);
        acc[rb] = __builtin_amdgcn_mfma_f32_16x16x32_bf16(a, bb[kk], acc[rb], 0, 0, 0);
      }
    }
#pragma unroll
    for (int rb = 0; rb < 8; ++rb) {
      int d0 = rb * 16 + ldiv * 4;
      f32x4 bv = *(const f32x4*)(bias + d0);
      if (m == 0) {
        f32x4 be = *(const f32x4*)(b_e + d0);
#pragma unroll
        for (int j = 0; j < 4; ++j) bv[j] += be[j];
      }
      f32x4 v = acc[rb];
#pragma unroll
      for (int j = 0; j < 4; ++j) v[j] += bv[j];
      uint2 pk;
      pk.x = cvtpk(v[0], v[1]);
      pk.y = cvtpk(v[2], v[3]);
      *(uint2*)(P + (size_t)row * (DD / 2) + d0 / 2) = pk;
    }
  }
}

__global__ void k_hist(const int* __restrict__ receivers, int* __restrict__ cnt) {
  int e = blockIdx.x * 256 + threadIdx.x;
  if (e < NE) atomicAdd(&cnt[receivers[e]], 1);
}

// Persistent fused edge kernel, streaming order, 2-deep software pipeline.
// s/rc(i+1) issued BEFORE E(i+1): next iteration's gather-address wait then
// drains only s/rc (in-order), leaving E loads in flight. No in-loop atomics.
__global__ __launch_bounds__(256, 4) void k_edge(
    const float* __restrict__ edges, const int* __restrict__ senders,
    const int* __restrict__ receivers, const unsigned short* __restrict__ WtE,
    const unsigned* __restrict__ P1h, const unsigned* __restrict__ Prh,
    const float* __restrict__ W_att, const float* __restrict__ b_att,
    float* __restrict__ out_edges, float* __restrict__ attb) {
  __shared__ char ldsW[32768];
  __shared__ float attw[DD];
  int tid = threadIdx.x;
  stage_w(WtE, ldsW, tid);
  if (tid < DD / 4) ((f32x4*)attw)[tid] = ((const f32x4*)W_att)[tid];
  __syncthreads();
  int wid = tid >> 6, l = tid & 63;
  int lmod = l & 15, ldiv = l >> 4;
  int wave = blockIdx.x * 4 + wid, nw = gridDim.x * 4;
  const int NB = NE / 16;
  float batt = b_att[0];

  int b = wave;
  if (b >= NB) return;

  f32x4 E[8];
  int s, rc;
  {
    int en = b * 16 + lmod;
    s = senders[en];
    rc = receivers[en];
    const f32x4* erow = (const f32x4*)(edges + (size_t)en * DD);
#pragma unroll
    for (int q = 0; q < 8; ++q)
      E[q] = __builtin_nontemporal_load(erow + ((q >> 1) * 8 + ldiv * 2 + (q & 1)));
  }

  while (b < NB) {
    int e = b * 16 + lmod;
    int bn = b + nw;
    // 1) gathers for current batch (s/rc arrived early; E may still be in flight)
    const unsigned* p1 = P1h + (size_t)s * (DD / 2);
    const unsigned* pr = Prh + (size_t)rc * (DD / 2);
    uint2 g1[8], gr[8];
#pragma unroll
    for (int rb = 0; rb < 8; ++rb) {
      int d2 = rb * 8 + ldiv * 2;
      g1[rb] = *(const uint2*)(p1 + d2);
      gr[rb] = *(const uint2*)(pr + d2);
    }
    // 2) consume E -> bf16 (waits on E only)
    short8 bb[4];
#pragma unroll
    for (int kk = 0; kk < 4; ++kk) bb[kk] = cvt8(E[2 * kk], E[2 * kk + 1]);
    // 3) next-batch loads: indices FIRST, then E rows (reuses freed registers)
    if (bn < NB) {
      int en = bn * 16 + lmod;
      s = senders[en];
      rc = receivers[en];
      const f32x4* erow = (const f32x4*)(edges + (size_t)en * DD);
#pragma unroll
      for (int q = 0; q < 8; ++q)
        E[q] = __builtin_nontemporal_load(erow + ((q >> 1) * 8 + ldiv * 2 + (q & 1)));
    }
    // 4) MFMA (LDS only)
    f32x4 acc[8] = {};
#pragma unroll
    for (int kk = 0; kk < 4; ++kk) {
#pragma unroll
      for (int rb = 0; rb < 8; ++rb) {
        short8 a = read_w(ldsW, rb * 16 + lmod, kk * 4 + ldiv);
        acc[rb] = __builtin_amdgcn_mfma_f32_16x16x32_bf16(a, bb[kk], acc[rb], 0, 0, 0);
      }
    }
    // 5) epilogue: counted vmcnt waits gathers only; next-batch loads stay in flight
    float* oe = out_edges + (size_t)e * DD;
    float att = 0.f;
#pragma unroll
    for (int rb = 0; rb < 8; ++rb) {
      int d0 = rb * 16 + ldiv * 4;
      f32x4 g1v = unpk(g1[rb]);
      f32x4 grv = unpk(gr[rb]);
      f32x4 wa = *(const f32x4*)(attw + d0);   // LDS read
      f32x4 v = acc[rb];
#pragma unroll
      for (int j = 0; j < 4; ++j) {
        float x = v[j] + g1v[j] + grv[j];
        v[j] = x;
        att += x * wa[j];
      }
      __builtin_nontemporal_store(v, (f32x4*)(oe + d0));
    }
    att += __shfl_xor(att, 16);
    att += __shfl_xor(att, 32);
    if (ldiv == 0) {
      float av = att + batt;
      av = (av >= 0.f) ? av : 0.01f * av;
      attb[e] = av;
    }
    b = bn;
  }
}

// Single-block shfl-based scan: 4 elems/thread, 13 chunks of 4096.
__global__ __launch_bounds__(1024) void k_scan(const int* __restrict__ cnt,
                                               int* __restrict__ offs) {
  __shared__ int wsum[16];
  __shared__ int sbase;
  int t = threadIdx.x;
  int lane = t & 63, wid = t >> 6;
  if (t == 0) { sbase = 0; offs[0] = 0; }
  __syncthreads();
  for (int c = 0; c < 13; ++c) {
    int i0 = c * 4096 + t * 4;
    int v0 = 0, v1 = 0, v2 = 0, v3 = 0;
    if (i0 + 3 < NN) {
      int4 v = *(const int4*)(cnt + i0);
      v0 = v.x; v1 = v.y; v2 = v.z; v3 = v.w;
    } else {
      if (i0 + 0 < NN) v0 = cnt[i0 + 0];
      if (i0 + 1 < NN) v1 = cnt[i0 + 1];
      if (i0 + 2 < NN) v2 = cnt[i0 + 2];
      if (i0 + 3 < NN) v3 = cnt[i0 + 3];
    }
    int p1 = v0, p2 = p1 + v1, p3 = p2 + v2, p4 = p3 + v3;
    int x = p4;
#pragma unroll
    for (int d = 1; d < 64; d <<= 1) {
      int o = __shfl_up(x, d, 64);
      if (lane >= d) x += o;
    }
    if (lane == 63) wsum[wid] = x;
    int excl_lane = x - p4;
    __syncthreads();
    int wbase = 0, tot = 0;
#pragma unroll
    for (int w2 = 0; w2 < 16; ++w2) {
      int sv = wsum[w2];
      if (w2 < wid) wbase += sv;
      tot += sv;
    }
    int base = sbase + wbase + excl_lane;
    if (i0 + 0 < NN) offs[i0 + 1] = base + p1;
    if (i0 + 1 < NN) offs[i0 + 2] = base + p2;
    if (i0 + 2 < NN) offs[i0 + 3] = base + p3;
    if (i0 + 3 < NN) offs[i0 + 4] = base + p4;
    __syncthreads();
    if (t == 0) sbase += tot;
    __syncthreads();
  }
}

__global__ void k_fill(const int* __restrict__ receivers, const int* __restrict__ offs,
                       int* __restrict__ cursor, int* __restrict__ eidx) {
  int e = blockIdx.x * 256 + threadIdx.x;
  if (e < NE) {
    int rc = receivers[e];
    int pos = offs[rc] + atomicAdd(&cursor[rc], 1);
    eidx[pos] = e;
  }
}

// Per-node softmax + weighted Pm aggregation (Pm packed bf16).
// 4 edges processed concurrently by lane groups (g = l>>4); lane (g,q) reads
// a uint4 (8 dims) of edge (i+g)'s Pm row; cross-group shfl reduce at the end.
__global__ __launch_bounds__(256) void k_node(
    const int* __restrict__ offs, const int* __restrict__ eidx,
    const int* __restrict__ senders, const float* __restrict__ attb,
    const unsigned* __restrict__ Pmh, float* __restrict__ out_nodes) {
  int wid = threadIdx.x >> 6, l = threadIdx.x & 63;
  int n = blockIdx.x * 4 + wid;
  if (n >= NN) return;
  int start = offs[n], end = offs[n + 1];
  int g = l >> 4, q = l & 15;
  float m = -3.4e38f, denom = 0.f;
  f32x4 sA = {0.f, 0.f, 0.f, 0.f}, sB = {0.f, 0.f, 0.f, 0.f};  // dims q*8 .. q*8+8
  for (int c = start; c < end; c += 64) {
    int rem = end - c;
    if (rem > 64) rem = 64;
    float a_l = -3.4e38f;
    int s_l = 0;
    if (l < rem) {
      int e = eidx[c + l];
      a_l = attb[e];
      s_l = senders[e];
    }
    float cm = a_l;
#pragma unroll
    for (int d = 1; d < 64; d <<= 1) cm = fmaxf(cm, __shfl_xor(cm, d));
    if (cm > m) {
      float sc = __expf(m - cm);   // first chunk: exp(-huge) = 0, state is 0 anyway
      denom *= sc;
#pragma unroll
      for (int j = 0; j < 4; ++j) { sA[j] *= sc; sB[j] *= sc; }
      m = cm;
    }
    float ex = (l < rem) ? __expf(a_l - m) : 0.f;
#pragma unroll
    for (int d = 1; d < 64; d <<= 1) ex += __shfl_xor(ex, d);
    denom += ex;
    for (int i = 0; i < rem; i += 4) {
      int ig = i + g;
      float a = __shfl(a_l, ig & 63);
      int sv = __shfl(s_l, ig & 63);
      if (ig < rem) {
        float w = __expf(a - m);
        uint4 u = *(const uint4*)(Pmh + (size_t)sv * (DD / 2) + q * 4);
        sA[0] += w * __uint_as_float(u.x << 16);
        sA[1] += w * __uint_as_float(u.x & 0xFFFF0000u);
        sA[2] += w * __uint_as_float(u.y << 16);
        sA[3] += w * __uint_as_float(u.y & 0xFFFF0000u);
        sB[0] += w * __uint_as_float(u.z << 16);
        sB[1] += w * __uint_as_float(u.z & 0xFFFF0000u);
        sB[2] += w * __uint_as_float(u.w << 16);
        sB[3] += w * __uint_as_float(u.w & 0xFFFF0000u);
      }
    }
  }
#pragma unroll
  for (int j = 0; j < 4; ++j) {
    sA[j] += __shfl_xor(sA[j], 16);
    sA[j] += __shfl_xor(sA[j], 32);
    sB[j] += __shfl_xor(sB[j], 16);
    sB[j] += __shfl_xor(sB[j], 32);
  }
  if (g == 0) {
    float inv = (end > start) ? 1.f / denom : 0.f;
#pragma unroll
    for (int j = 0; j < 4; ++j) { sA[j] *= inv; sB[j] *= inv; }
    float* orow = out_nodes + (size_t)n * DD + q * 8;
    *(f32x4*)(orow) = sA;
    *(f32x4*)(orow + 4) = sB;
  }
}

extern "C" void kernel_launch(void* const* d_in, const int* in_sizes, int n_in,
                              void* d_out, int out_size, void* d_ws, size_t ws_size,
                              hipStream_t stream) {
  (void)in_sizes; (void)n_in; (void)out_size; (void)ws_size;
  const float* nodes = (const float*)d_in[0];
  const float* edges = (const float*)d_in[1];
  const int* senders = (const int*)d_in[2];
  const int* receivers = (const int*)d_in[3];
  const float* W_s1 = (const float*)d_in[4];
  const float* b_s1 = (const float*)d_in[5];
  const float* W_r = (const float*)d_in[6];
  const float* b_r = (const float*)d_in[7];
  const float* W_e = (const float*)d_in[8];
  const float* b_e = (const float*)d_in[9];
  const float* W_att = (const float*)d_in[10];
  const float* b_att = (const float*)d_in[11];
  const float* W_m = (const float*)d_in[12];
  const float* b_m = (const float*)d_in[13];

  float* out_nodes = (float*)d_out;
  float* out_edges = out_nodes + (size_t)NN * DD;

  char* w = (char*)d_ws;
  unsigned short* Wt = (unsigned short*)w; w += (size_t)4 * DD * DD * 2;   // 128 KB
  unsigned* P1h = (unsigned*)w; w += (size_t)NN * (DD / 2) * 4;
  unsigned* Prh = (unsigned*)w; w += (size_t)NN * (DD / 2) * 4;
  unsigned* Pmh = (unsigned*)w; w += (size_t)NN * (DD / 2) * 4;
  float* attb = (float*)w; w += (size_t)NE * 4;
  int* eidx = (int*)w; w += (size_t)NE * 4;
  int* cnt = (int*)w; w += (size_t)NN * 4;
  int* cursor = (int*)w; w += (size_t)NN * 4;
  int* offs = (int*)w; w += (size_t)(NN + 1) * 4;

  hipMemsetAsync(cnt, 0, (size_t)NN * 8, stream);  // cnt + cursor (contiguous)

  k_prep<<<64, 256, 0, stream>>>(W_s1, W_r, W_m, W_e, Wt);
  k_hist<<<(NE + 255) / 256, 256, 0, stream>>>(receivers, cnt);
  k_nodeproj<<<dim3(256, 3), 256, 0, stream>>>(nodes, Wt, b_s1, b_r, b_m, b_e, P1h, Prh, Pmh);
  k_edge<<<1024, 256, 0, stream>>>(edges, senders, receivers, Wt + 3 * 16384,
                                   P1h, Prh, W_att, b_att, out_edges, attb);
  k_scan<<<1, 1024, 0, stream>>>(cnt, offs);
  k_fill<<<(NE + 255) / 256, 256, 0, stream>>>(receivers, offs, cursor, eidx);
  k_node<<<NN / 4, 256, 0, stream>>>(offs, eidx, senders, attb, Pmh, out_nodes);
}

// Round 13
// 388.303 us; speedup vs baseline: 1.2577x; 1.2577x over previous
//
#include <hip/hip_runtime.h>
#include <hip/hip_bf16.h>
#include <cstdint>
#include <cstddef>

#define NN 50000
#define NE 800000
#define DD 128

typedef __attribute__((ext_vector_type(8))) short short8;
typedef __attribute__((ext_vector_type(4))) float f32x4;

__device__ __forceinline__ unsigned short f2bf(float f) {
  unsigned u = __float_as_uint(f);
  u = (u + 0x7FFFu + ((u >> 16) & 1u)) >> 16;
  return (unsigned short)u;
}

// Convert 4 weight matrices [k][col] f32 -> transposed bf16 [col][k] (linear)
__global__ void k_prep(const float* __restrict__ Ws1, const float* __restrict__ Wr,
                       const float* __restrict__ Wm, const float* __restrict__ We,
                       unsigned short* __restrict__ Wt) {
  int i = blockIdx.x * blockDim.x + threadIdx.x;
  for (int idx = i; idx < 4 * DD * DD; idx += gridDim.x * blockDim.x) {
    int m = idx >> 14, r = idx & 16383, col = r >> 7, k = r & 127;
    const float* src = (m == 0) ? Ws1 : (m == 1) ? Wr : (m == 2) ? Wm : We;
    Wt[idx] = f2bf(src[k * DD + col]);
  }
}

__device__ __forceinline__ unsigned cvtpk(float lo, float hi) {
  unsigned r;
  asm("v_cvt_pk_bf16_f32 %0, %1, %2" : "=v"(r) : "v"(lo), "v"(hi));
  return r;
}

__device__ __forceinline__ short8 cvt8(f32x4 f0, f32x4 f1) {
  union { short8 s; unsigned u[4]; } t;
  t.u[0] = cvtpk(f0[0], f0[1]);
  t.u[1] = cvtpk(f0[2], f0[3]);
  t.u[2] = cvtpk(f1[0], f1[1]);
  t.u[3] = cvtpk(f1[2], f1[3]);
  return t.s;
}

__device__ __forceinline__ f32x4 unpk(uint2 u) {
  f32x4 v;
  v[0] = __uint_as_float(u.x << 16);
  v[1] = __uint_as_float(u.x & 0xFFFF0000u);
  v[2] = __uint_as_float(u.y << 16);
  v[3] = __uint_as_float(u.y & 0xFFFF0000u);
  return v;
}

// Stage 32KB W ([col][k] bf16) into LDS. Chunk (col, slot∈[0,16)) of 16B goes to
// col*256 + ((slot^col)&15)*16 — per-read-instruction bank-groups are uniform.
__device__ __forceinline__ void stage_w(const unsigned short* __restrict__ Wt,
                                        char* __restrict__ lds, int tid) {
#pragma unroll
  for (int c = 0; c < 8; ++c) {
    int ci = tid * 8 + c;
    int col = ci >> 4, slot = ci & 15;
    uint4 v = *(const uint4*)(Wt + ci * 8);
    *(uint4*)(lds + col * 256 + ((slot ^ col) & 15) * 16) = v;
  }
}

__device__ __forceinline__ short8 read_w(const char* __restrict__ lds, int col, int slot) {
  return *(const short8*)(lds + col * 256 + ((slot ^ col) & 15) * 16);
}

// Persistent 3-plane node projection. Plane 0 bias = b_s1 + b_e (folded).
// All planes written as packed bf16 (halves gather traffic downstream).
__global__ __launch_bounds__(256, 4) void k_nodeproj(
    const float* __restrict__ nodes, const unsigned short* __restrict__ Wt,
    const float* __restrict__ b_s1, const float* __restrict__ b_r, const float* __restrict__ b_m,
    const float* __restrict__ b_e,
    unsigned* __restrict__ P1h, unsigned* __restrict__ Prh, unsigned* __restrict__ Pmh) {
  __shared__ char ldsW[32768];
  int m = blockIdx.y;
  int tid = threadIdx.x;
  stage_w(Wt + m * 16384, ldsW, tid);
  __syncthreads();
  const float* bias = (m == 0) ? b_s1 : (m == 1) ? b_r : b_m;
  unsigned* P = (m == 0) ? P1h : (m == 1) ? Prh : Pmh;
  int wid = tid >> 6, l = tid & 63;
  int lmod = l & 15, ldiv = l >> 4;
  int wave = blockIdx.x * 4 + wid, nw = gridDim.x * 4;
  for (int b = wave; b < NN / 16; b += nw) {
    int row = b * 16 + lmod;
    const float* nrow = nodes + (size_t)row * DD;
    short8 bb[4];
#pragma unroll
    for (int kk = 0; kk < 4; ++kk) {
      const f32x4* p = (const f32x4*)(nrow + kk * 32 + ldiv * 8);
      bb[kk] = cvt8(p[0], p[1]);
    }
    f32x4 acc[8] = {};
#pragma unroll
    for (int kk = 0; kk < 4; ++kk) {
#pragma unroll
      for (int rb = 0; rb < 8; ++rb) {
        short8 a = read_w(ldsW, rb * 16 + lmod, kk * 4 + ldiv);
        acc[rb] = __builtin_amdgcn_mfma_f32_16x16x32_bf16(a, bb[kk], acc[rb], 0, 0, 0);
      }
    }
#pragma unroll
    for (int rb = 0; rb < 8; ++rb) {
      int d0 = rb * 16 + ldiv * 4;
      f32x4 bv = *(const f32x4*)(bias + d0);
      if (m == 0) {
        f32x4 be = *(const f32x4*)(b_e + d0);
#pragma unroll
        for (int j = 0; j < 4; ++j) bv[j] += be[j];
      }
      f32x4 v = acc[rb];
#pragma unroll
      for (int j = 0; j < 4; ++j) v[j] += bv[j];
      uint2 pk;
      pk.x = cvtpk(v[0], v[1]);
      pk.y = cvtpk(v[2], v[3]);
      *(uint2*)(P + (size_t)row * (DD / 2) + d0 / 2) = pk;
    }
  }
}

// Persistent fused edge kernel, streaming order, 2-deep software pipeline.
// (256,3)/grid 768: the 137-reg live set needs the 170-reg budget — (256,4)
// spilled twice (r8, r12). Indices issued BEFORE E rows: the gather-address
// wait at loop top drains only idx (vmcnt leaves E in flight), so gathers(i)
// overlap E(i)'s tail and E(i+1) is only waited at cvt(i+1).
__global__ __launch_bounds__(256, 3) void k_edge(
    const float* __restrict__ edges, const int* __restrict__ senders,
    const int* __restrict__ receivers, const unsigned short* __restrict__ WtE,
    const unsigned* __restrict__ P1h, const unsigned* __restrict__ Prh,
    const float* __restrict__ W_att, const float* __restrict__ b_att,
    float* __restrict__ out_edges, float* __restrict__ attb, int* __restrict__ cnt) {
  __shared__ char ldsW[32768];
  __shared__ float attw[DD];
  int tid = threadIdx.x;
  stage_w(WtE, ldsW, tid);
  if (tid < DD / 4) ((f32x4*)attw)[tid] = ((const f32x4*)W_att)[tid];
  __syncthreads();
  int wid = tid >> 6, l = tid & 63;
  int lmod = l & 15, ldiv = l >> 4;
  int wave = blockIdx.x * 4 + wid, nw = gridDim.x * 4;
  const int NB = NE / 16;
  float batt = b_att[0];

  int b = wave;
  if (b >= NB) return;

  f32x4 E[8];
  int s, rc;
  {
    int en = b * 16 + lmod;
    s = senders[en];            // idx first
    rc = receivers[en];
    const f32x4* erow = (const f32x4*)(edges + (size_t)en * DD);
#pragma unroll
    for (int q = 0; q < 8; ++q)
      E[q] = __builtin_nontemporal_load(erow + ((q >> 1) * 8 + ldiv * 2 + (q & 1)));
  }

  while (b < NB) {
    int e = b * 16 + lmod;
    int bn = b + nw;
    // 1) gathers for current batch (idx already retired; E may still be in flight)
    const unsigned* p1 = P1h + (size_t)s * (DD / 2);
    const unsigned* pr = Prh + (size_t)rc * (DD / 2);
    uint2 g1[8], gr[8];
#pragma unroll
    for (int rb = 0; rb < 8; ++rb) {
      int d2 = rb * 8 + ldiv * 2;
      g1[rb] = *(const uint2*)(p1 + d2);
      gr[rb] = *(const uint2*)(pr + d2);
    }
    int rc0 = rc;
    // 2) consume E -> bf16 (waits E only; gathers stay in flight)
    short8 bb[4];
#pragma unroll
    for (int kk = 0; kk < 4; ++kk) bb[kk] = cvt8(E[2 * kk], E[2 * kk + 1]);
    // 3) next-batch loads: indices FIRST, then E rows (reuses freed registers)
    if (bn < NB) {
      int en = bn * 16 + lmod;
      s = senders[en];
      rc = receivers[en];
      const f32x4* erow = (const f32x4*)(edges + (size_t)en * DD);
#pragma unroll
      for (int q = 0; q < 8; ++q)
        E[q] = __builtin_nontemporal_load(erow + ((q >> 1) * 8 + ldiv * 2 + (q & 1)));
    }
    // 4) MFMA (LDS only)
    f32x4 acc[8] = {};
#pragma unroll
    for (int kk = 0; kk < 4; ++kk) {
#pragma unroll
      for (int rb = 0; rb < 8; ++rb) {
        short8 a = read_w(ldsW, rb * 16 + lmod, kk * 4 + ldiv);
        acc[rb] = __builtin_amdgcn_mfma_f32_16x16x32_bf16(a, bb[kk], acc[rb], 0, 0, 0);
      }
    }
    // 5) epilogue: counted vmcnt waits gathers only; next-batch idx+E stay in flight
    float* oe = out_edges + (size_t)e * DD;
    float att = 0.f;
#pragma unroll
    for (int rb = 0; rb < 8; ++rb) {
      int d0 = rb * 16 + ldiv * 4;
      f32x4 g1v = unpk(g1[rb]);
      f32x4 grv = unpk(gr[rb]);
      f32x4 wa = *(const f32x4*)(attw + d0);   // LDS read
      f32x4 v = acc[rb];
#pragma unroll
      for (int j = 0; j < 4; ++j) {
        float x = v[j] + g1v[j] + grv[j];
        v[j] = x;
        att += x * wa[j];
      }
      __builtin_nontemporal_store(v, (f32x4*)(oe + d0));
    }
    att += __shfl_xor(att, 16);
    att += __shfl_xor(att, 32);
    if (ldiv == 0) {
      float av = att + batt;
      av = (av >= 0.f) ? av : 0.01f * av;
      attb[e] = av;
      atomicAdd(&cnt[rc0], 1);
    }
    b = bn;
  }
}

// Single-block shfl-based scan: 4 elems/thread, 13 chunks of 4096.
__global__ __launch_bounds__(1024) void k_scan(const int* __restrict__ cnt,
                                               int* __restrict__ offs) {
  __shared__ int wsum[16];
  __shared__ int sbase;
  int t = threadIdx.x;
  int lane = t & 63, wid = t >> 6;
  if (t == 0) { sbase = 0; offs[0] = 0; }
  __syncthreads();
  for (int c = 0; c < 13; ++c) {
    int i0 = c * 4096 + t * 4;
    int v0 = 0, v1 = 0, v2 = 0, v3 = 0;
    if (i0 + 3 < NN) {
      int4 v = *(const int4*)(cnt + i0);
      v0 = v.x; v1 = v.y; v2 = v.z; v3 = v.w;
    } else {
      if (i0 + 0 < NN) v0 = cnt[i0 + 0];
      if (i0 + 1 < NN) v1 = cnt[i0 + 1];
      if (i0 + 2 < NN) v2 = cnt[i0 + 2];
      if (i0 + 3 < NN) v3 = cnt[i0 + 3];
    }
    int p1 = v0, p2 = p1 + v1, p3 = p2 + v2, p4 = p3 + v3;
    int x = p4;
#pragma unroll
    for (int d = 1; d < 64; d <<= 1) {
      int o = __shfl_up(x, d, 64);
      if (lane >= d) x += o;
    }
    if (lane == 63) wsum[wid] = x;
    int excl_lane = x - p4;
    __syncthreads();
    int wbase = 0, tot = 0;
#pragma unroll
    for (int w2 = 0; w2 < 16; ++w2) {
      int sv = wsum[w2];
      if (w2 < wid) wbase += sv;
      tot += sv;
    }
    int base = sbase + wbase + excl_lane;
    if (i0 + 0 < NN) offs[i0 + 1] = base + p1;
    if (i0 + 1 < NN) offs[i0 + 2] = base + p2;
    if (i0 + 2 < NN) offs[i0 + 3] = base + p3;
    if (i0 + 3 < NN) offs[i0 + 4] = base + p4;
    __syncthreads();
    if (t == 0) sbase += tot;
    __syncthreads();
  }
}

__global__ void k_fill(const int* __restrict__ receivers, const int* __restrict__ offs,
                       int* __restrict__ cursor, int* __restrict__ eidx) {
  int e = blockIdx.x * 256 + threadIdx.x;
  if (e < NE) {
    int rc = receivers[e];
    int pos = offs[rc] + atomicAdd(&cursor[rc], 1);
    eidx[pos] = e;
  }
}

// Per-node softmax + weighted Pm aggregation (Pm packed bf16).
// 4 edges processed concurrently by lane groups (g = l>>4); lane (g,q) reads
// a uint4 (8 dims) of edge (i+g)'s Pm row; cross-group shfl reduce at the end.
__global__ __launch_bounds__(256) void k_node(
    const int* __restrict__ offs, const int* __restrict__ eidx,
    const int* __restrict__ senders, const float* __restrict__ attb,
    const unsigned* __restrict__ Pmh, float* __restrict__ out_nodes) {
  int wid = threadIdx.x >> 6, l = threadIdx.x & 63;
  int n = blockIdx.x * 4 + wid;
  if (n >= NN) return;
  int start = offs[n], end = offs[n + 1];
  int g = l >> 4, q = l & 15;
  float m = -3.4e38f, denom = 0.f;
  f32x4 sA = {0.f, 0.f, 0.f, 0.f}, sB = {0.f, 0.f, 0.f, 0.f};  // dims q*8 .. q*8+8
  for (int c = start; c < end; c += 64) {
    int rem = end - c;
    if (rem > 64) rem = 64;
    float a_l = -3.4e38f;
    int s_l = 0;
    if (l < rem) {
      int e = eidx[c + l];
      a_l = attb[e];
      s_l = senders[e];
    }
    float cm = a_l;
#pragma unroll
    for (int d = 1; d < 64; d <<= 1) cm = fmaxf(cm, __shfl_xor(cm, d));
    if (cm > m) {
      float sc = __expf(m - cm);   // first chunk: exp(-huge) = 0, state is 0 anyway
      denom *= sc;
#pragma unroll
      for (int j = 0; j < 4; ++j) { sA[j] *= sc; sB[j] *= sc; }
      m = cm;
    }
    float ex = (l < rem) ? __expf(a_l - m) : 0.f;
#pragma unroll
    for (int d = 1; d < 64; d <<= 1) ex += __shfl_xor(ex, d);
    denom += ex;
    for (int i = 0; i < rem; i += 4) {
      int ig = i + g;
      float a = __shfl(a_l, ig & 63);
      int sv = __shfl(s_l, ig & 63);
      if (ig < rem) {
        float w = __expf(a - m);
        uint4 u = *(const uint4*)(Pmh + (size_t)sv * (DD / 2) + q * 4);
        sA[0] += w * __uint_as_float(u.x << 16);
        sA[1] += w * __uint_as_float(u.x & 0xFFFF0000u);
        sA[2] += w * __uint_as_float(u.y << 16);
        sA[3] += w * __uint_as_float(u.y & 0xFFFF0000u);
        sB[0] += w * __uint_as_float(u.z << 16);
        sB[1] += w * __uint_as_float(u.z & 0xFFFF0000u);
        sB[2] += w * __uint_as_float(u.w << 16);
        sB[3] += w * __uint_as_float(u.w & 0xFFFF0000u);
      }
    }
  }
#pragma unroll
  for (int j = 0; j < 4; ++j) {
    sA[j] += __shfl_xor(sA[j], 16);
    sA[j] += __shfl_xor(sA[j], 32);
    sB[j] += __shfl_xor(sB[j], 16);
    sB[j] += __shfl_xor(sB[j], 32);
  }
  if (g == 0) {
    float inv = (end > start) ? 1.f / denom : 0.f;
#pragma unroll
    for (int j = 0; j < 4; ++j) { sA[j] *= inv; sB[j] *= inv; }
    float* orow = out_nodes + (size_t)n * DD + q * 8;
    *(f32x4*)(orow) = sA;
    *(f32x4*)(orow + 4) = sB;
  }
}

extern "C" void kernel_launch(void* const* d_in, const int* in_sizes, int n_in,
                              void* d_out, int out_size, void* d_ws, size_t ws_size,
                              hipStream_t stream) {
  (void)in_sizes; (void)n_in; (void)out_size; (void)ws_size;
  const float* nodes = (const float*)d_in[0];
  const float* edges = (const float*)d_in[1];
  const int* senders = (const int*)d_in[2];
  const int* receivers = (const int*)d_in[3];
  const float* W_s1 = (const float*)d_in[4];
  const float* b_s1 = (const float*)d_in[5];
  const float* W_r = (const float*)d_in[6];
  const float* b_r = (const float*)d_in[7];
  const float* W_e = (const float*)d_in[8];
  const float* b_e = (const float*)d_in[9];
  const float* W_att = (const float*)d_in[10];
  const float* b_att = (const float*)d_in[11];
  const float* W_m = (const float*)d_in[12];
  const float* b_m = (const float*)d_in[13];

  float* out_nodes = (float*)d_out;
  float* out_edges = out_nodes + (size_t)NN * DD;

  char* w = (char*)d_ws;
  unsigned short* Wt = (unsigned short*)w; w += (size_t)4 * DD * DD * 2;   // 128 KB
  unsigned* P1h = (unsigned*)w; w += (size_t)NN * (DD / 2) * 4;
  unsigned* Prh = (unsigned*)w; w += (size_t)NN * (DD / 2) * 4;
  unsigned* Pmh = (unsigned*)w; w += (size_t)NN * (DD / 2) * 4;
  float* attb = (float*)w; w += (size_t)NE * 4;
  int* eidx = (int*)w; w += (size_t)NE * 4;
  int* cnt = (int*)w; w += (size_t)NN * 4;
  int* cursor = (int*)w; w += (size_t)NN * 4;
  int* offs = (int*)w; w += (size_t)(NN + 1) * 4;

  hipMemsetAsync(cnt, 0, (size_t)NN * 8, stream);  // cnt + cursor (contiguous)

  k_prep<<<64, 256, 0, stream>>>(W_s1, W_r, W_m, W_e, Wt);
  k_nodeproj<<<dim3(256, 3), 256, 0, stream>>>(nodes, Wt, b_s1, b_r, b_m, b_e, P1h, Prh, Pmh);
  k_edge<<<768, 256, 0, stream>>>(edges, senders, receivers, Wt + 3 * 16384,
                                  P1h, Prh, W_att, b_att, out_edges, attb, cnt);
  k_scan<<<1, 1024, 0, stream>>>(cnt, offs);
  k_fill<<<(NE + 255) / 256, 256, 0, stream>>>(receivers, offs, cursor, eidx);
  k_node<<<NN / 4, 256, 0, stream>>>(offs, eidx, senders, attb, Pmh, out_nodes);
}